// Round 2
// baseline (457.393 us; speedup 1.0000x reference)
//
#include <hip/hip_runtime.h>

typedef unsigned short u16;
typedef unsigned int u32;
typedef __bf16 bf16x8 __attribute__((ext_vector_type(8)));
typedef float f32x4 __attribute__((ext_vector_type(4)));

#define MTOT 8192
#define DM 1024
#define DI 256
#define TT 2048

__device__ __forceinline__ u16 f2bf(float f) {
    u32 u = __float_as_uint(f);
    return (u16)((u + 0x7fffu + ((u >> 16) & 1u)) >> 16);
}

// ================= prep: X cvt + 6 weight transposes in ONE launch =================
// blocks [0,1024): grid-stride cvt of X (8.4M f32 -> bf16)
// blocks [1024,4096): 32x32 transpose tiles for the 6 weights
__device__ __forceinline__ void transpose_tile(const float* __restrict__ in,
                                               u16* __restrict__ out, int K, int N,
                                               int bx, int by) {
    __shared__ float t[32][33];
    int n0 = bx * 32, k0 = by * 32;
    int tx = threadIdx.x & 31, ty = threadIdx.x >> 5;
    #pragma unroll
    for (int i = ty; i < 32; i += 8) t[i][tx] = in[(long)(k0 + i) * N + n0 + tx];
    __syncthreads();
    #pragma unroll
    for (int i = ty; i < 32; i += 8) out[(long)(n0 + i) * K + k0 + tx] = f2bf(t[tx][i]);
}

__global__ __launch_bounds__(256) void prep_kernel(
    const float* __restrict__ x, u16* __restrict__ Xb,
    const float* __restrict__ wq, const float* __restrict__ wk, u16* __restrict__ Wqk_t,
    const float* __restrict__ wv, u16* __restrict__ Wv_t,
    const float* __restrict__ wo, u16* __restrict__ Wo_t,
    const float* __restrict__ w1, u16* __restrict__ W1_t,
    const float* __restrict__ w2, u16* __restrict__ W2_t)
{
    int b = blockIdx.x;
    if (b < 1024) {
        long n4 = (long)MTOT * DM / 4;
        long i = (long)b * 256 + threadIdx.x;
        long stride = 1024L * 256;
        for (; i < n4; i += stride) {
            float4 v = reinterpret_cast<const float4*>(x)[i];
            union { u16 u[4]; uint2 p; } o;
            o.u[0] = f2bf(v.x); o.u[1] = f2bf(v.y); o.u[2] = f2bf(v.z); o.u[3] = f2bf(v.w);
            reinterpret_cast<uint2*>(Xb)[i] = o.p;
        }
        return;
    }
    b -= 1024;
    if (b < 256)        { transpose_tile(wq, Wqk_t,              1024,  256, b & 7,  b >> 3); return; }
    b -= 256;
    if (b < 256)        { transpose_tile(wk, Wqk_t + 256 * 1024, 1024,  256, b & 7,  b >> 3); return; }
    b -= 256;
    if (b < 1024)       { transpose_tile(wv, Wv_t,               1024, 1024, b & 31, b >> 5); return; }
    b -= 1024;
    if (b < 1024)       { transpose_tile(wo, Wo_t,               1024, 1024, b & 31, b >> 5); return; }
    b -= 1024;
    if (b < 256)        { transpose_tile(w1, W1_t,               1024,  256, b & 7,  b >> 3); return; }
    b -= 256;
    /* w2: (256,1024) -> (1024,256): tiles 32 x 8 */
    transpose_tile(w2, W2_t, 256, 1024, b & 31, b >> 5);
}

// ---------------- row softmax over T=2048, in-place fp32 + bf16 copy ----------------
__global__ __launch_bounds__(256) void softmax_kernel(float* __restrict__ S, u16* __restrict__ Sb) {
    long row = blockIdx.x;
    float* p = S + row * (long)TT;
    int tid = threadIdx.x;
    float4 v0 = reinterpret_cast<float4*>(p)[tid * 2];
    float4 v1 = reinterpret_cast<float4*>(p)[tid * 2 + 1];
    float vv[8] = {v0.x, v0.y, v0.z, v0.w, v1.x, v1.y, v1.z, v1.w};
    float m = vv[0];
    #pragma unroll
    for (int j = 1; j < 8; ++j) m = fmaxf(m, vv[j]);
    #pragma unroll
    for (int off = 32; off; off >>= 1) m = fmaxf(m, __shfl_xor(m, off));
    __shared__ float redm[4], reds[4];
    if ((tid & 63) == 0) redm[tid >> 6] = m;
    __syncthreads();
    m = fmaxf(fmaxf(redm[0], redm[1]), fmaxf(redm[2], redm[3]));
    float s = 0.f;
    #pragma unroll
    for (int j = 0; j < 8; ++j) { vv[j] = __expf(vv[j] - m); s += vv[j]; }
    #pragma unroll
    for (int off = 32; off; off >>= 1) s += __shfl_xor(s, off);
    if ((tid & 63) == 0) reds[tid >> 6] = s;
    __syncthreads();
    s = reds[0] + reds[1] + reds[2] + reds[3];
    float inv = 1.0f / s;
    #pragma unroll
    for (int j = 0; j < 8; ++j) vv[j] *= inv;
    reinterpret_cast<float4*>(p)[tid * 2]     = make_float4(vv[0], vv[1], vv[2], vv[3]);
    reinterpret_cast<float4*>(p)[tid * 2 + 1] = make_float4(vv[4], vv[5], vv[6], vv[7]);
    union { u16 u[8]; uint4 q; } pk;
    #pragma unroll
    for (int j = 0; j < 8; ++j) pk.u[j] = f2bf(vv[j]);
    reinterpret_cast<uint4*>(Sb + row * (long)TT)[tid] = pk.q;
}

// ---------------- GEMM body: C = A (M,K) @ Bt^T, Bt stored (N,K). ----------------
// m97 structure: 128x128 tile, BK=64, 4 waves, global_load_lds(16B),
// XOR-swizzle (linear LDS dest + pre-swizzled global source + swizzled ds_read).
// MODE: 0 = bf16 C
//       2 = fp32 C * scale    3 = bf16 relu(C + bias)
//       4 = Cf = addend + C + bias, Cb = bf16(Cf)
//       5 = Cf = addend + C + bias
template<int MODE>
__device__ __forceinline__ void gemm_body(
    u16* As, u16* Bs,
    const u16* __restrict__ A, int lda,
    const u16* __restrict__ Bt, int ldb,
    u16* __restrict__ Cb, int ldcb,
    float* __restrict__ Cf, int ldcf,
    int K, float scale,
    const float* __restrict__ bias,
    const float* __restrict__ addend,
    long tile_m, long tile_n)
{
    const int tid = threadIdx.x;
    const int w = tid >> 6;
    const int l = tid & 63;
    const int lane15 = l & 15;
    const int lhi = l >> 4;

    // staging: each issue i covers 32 rows; lane l -> row w*8 + (l>>3) within the
    // 32-row chunk, 16B chunk (l&7) XOR-swizzled by row&7 (= l>>3).
    const int srow = w * 8 + (l >> 3);
    const int scol = (((l & 7) ^ (l >> 3)) << 4) >> 1; // element offset in row

    const u16* aptr = A + (tile_m + srow) * (long)lda + scol;
    const u16* bptr = Bt + (tile_n + srow) * (long)ldb + scol;

    f32x4 acc[4][4] = {};

    const int wr = (w >> 1) * 64;
    const int wc = (w & 1) * 64;

    for (int k0 = 0; k0 < K; k0 += 64) {
        #pragma unroll
        for (int i = 0; i < 4; ++i) {
            __builtin_amdgcn_global_load_lds(
                (const __attribute__((address_space(1))) void*)(aptr + (long)i * 32 * lda + k0),
                (__attribute__((address_space(3))) void*)((char*)As + i * 4096 + w * 1024),
                16, 0, 0);
        }
        #pragma unroll
        for (int i = 0; i < 4; ++i) {
            __builtin_amdgcn_global_load_lds(
                (const __attribute__((address_space(1))) void*)(bptr + (long)i * 32 * ldb + k0),
                (__attribute__((address_space(3))) void*)((char*)Bs + i * 4096 + w * 1024),
                16, 0, 0);
        }
        __syncthreads();
        #pragma unroll
        for (int kk = 0; kk < 2; ++kk) {
            bf16x8 af[4], bfr[4];
            const int kb = (kk * 32 + lhi * 8) * 2; // byte offset of k within row
            #pragma unroll
            for (int m = 0; m < 4; ++m) {
                int r = wr + m * 16 + lane15;
                af[m] = *reinterpret_cast<const bf16x8*>(
                    (const char*)As + r * 128 + (kb ^ ((r & 7) << 4)));
            }
            #pragma unroll
            for (int n = 0; n < 4; ++n) {
                int r = wc + n * 16 + lane15;
                bfr[n] = *reinterpret_cast<const bf16x8*>(
                    (const char*)Bs + r * 128 + (kb ^ ((r & 7) << 4)));
            }
            #pragma unroll
            for (int m = 0; m < 4; ++m)
                #pragma unroll
                for (int n = 0; n < 4; ++n)
                    acc[m][n] = __builtin_amdgcn_mfma_f32_16x16x32_bf16(
                        af[m], bfr[n], acc[m][n], 0, 0, 0);
        }
        __syncthreads();
    }

    // epilogue: C/D layout col = lane&15, row = (lane>>4)*4 + reg (m89-verified)
    #pragma unroll
    for (int m = 0; m < 4; ++m) {
        #pragma unroll
        for (int n = 0; n < 4; ++n) {
            long grow0 = tile_m + wr + m * 16 + lhi * 4;
            long gcol  = tile_n + wc + n * 16 + lane15;
            #pragma unroll
            for (int r = 0; r < 4; ++r) {
                long grow = grow0 + r;
                float v = acc[m][n][r];
                if (MODE == 2) v *= scale;
                if (MODE == 3 || MODE == 4 || MODE == 5) v += bias[gcol];
                if (MODE == 4 || MODE == 5) v += addend[grow * (long)ldcf + gcol];
                if (MODE == 3) v = fmaxf(v, 0.0f);
                if (MODE == 0 || MODE == 3 || MODE == 4) Cb[grow * (long)ldcb + gcol] = f2bf(v);
                if (MODE == 2 || MODE == 4 || MODE == 5) Cf[grow * (long)ldcf + gcol] = v;
            }
        }
    }
}

// XCD-chunked bijective swizzle (valid because all grids are %8==0):
// hardware round-robins bid across 8 XCDs; logical id (bid&7)*cpx + bid>>3
// gives XCD j the contiguous logical chunk [j*cpx, (j+1)*cpx).
__device__ __forceinline__ int xcd_swizzle(int bid, int nb) {
    return (bid & 7) * (nb >> 3) + (bid >> 3);
}

template<int MODE>
__global__ __launch_bounds__(256) void gemm_bt(
    const u16* __restrict__ A, long sA, int lda,
    const u16* __restrict__ Bt, long sB, int ldb,
    u16* __restrict__ Cb, long sCb, int ldcb,
    float* __restrict__ Cf, long sCf, int ldcf,
    int K, float scale,
    const float* __restrict__ bias,
    const float* __restrict__ addend, long sAdd,
    int gx, int gy)
{
    __shared__ __attribute__((aligned(16))) u16 As[128 * 64];
    __shared__ __attribute__((aligned(16))) u16 Bs[128 * 64];

    int lid = xcd_swizzle(blockIdx.x, gridDim.x);
    int x = lid % gx;
    int t = lid / gx;
    int y = t % gy;
    int z = t / gy;

    gemm_body<MODE>(As, Bs,
                    A + (long)z * sA, lda, Bt + (long)z * sB, ldb,
                    Cb + (long)z * sCb, ldcb, Cf + (long)z * sCf, ldcf,
                    K, scale, bias,
                    addend ? addend + (long)z * sAdd : addend,
                    (long)y * 128, (long)x * 128);
}

// Merged [Q|K] GEMM + V^T GEMM (independent, both mode 0) in one 768-block dispatch:
// blocks' logical ids [0,256) -> QK = Xb @ Wqk_t^T (8192,512), gx=4 gy=64
// logical ids [256,768) -> V^T = Wv_t @ Xb^T (1024,8192), gx=64 gy=8
__global__ __launch_bounds__(256) void gemm_qkv(
    const u16* __restrict__ Xb, const u16* __restrict__ Wqk_t, u16* __restrict__ QKb,
    const u16* __restrict__ Wv_t, u16* __restrict__ Vt)
{
    __shared__ __attribute__((aligned(16))) u16 As[128 * 64];
    __shared__ __attribute__((aligned(16))) u16 Bs[128 * 64];

    int lid = xcd_swizzle(blockIdx.x, gridDim.x);
    if (lid < 256) {
        int x = lid & 3, y = lid >> 2;
        gemm_body<0>(As, Bs, Xb, 1024, Wqk_t, 1024, QKb, 512,
                     (float*)nullptr, 0, 1024, 1.0f,
                     (const float*)nullptr, (const float*)nullptr,
                     (long)y * 128, (long)x * 128);
    } else {
        int l2 = lid - 256;
        int x = l2 & 63, y = l2 >> 6;
        gemm_body<0>(As, Bs, Wv_t, 1024, Xb, 1024, Vt, 8192,
                     (float*)nullptr, 0, 8192, 1.0f,
                     (const float*)nullptr, (const float*)nullptr,
                     (long)y * 128, (long)x * 128);
    }
}

extern "C" void kernel_launch(void* const* d_in, const int* in_sizes, int n_in,
                              void* d_out, int out_size, void* d_ws, size_t ws_size,
                              hipStream_t stream)
{
    const float* x  = (const float*)d_in[0];
    const float* wq = (const float*)d_in[1];
    const float* wk = (const float*)d_in[2];
    const float* wv = (const float*)d_in[3];
    const float* wo = (const float*)d_in[4];
    const float* bo = (const float*)d_in[5];
    const float* w1 = (const float*)d_in[6];
    const float* b1 = (const float*)d_in[7];
    const float* w2 = (const float*)d_in[8];
    const float* b2 = (const float*)d_in[9];

    float* out_f  = (float*)d_out;
    float* attn_f = out_f + (long)MTOT * DM;  // second output, (4,2048,2048) fp32

    char* ws = (char*)d_ws;
    u16* Xb    = (u16*)(ws + 0);           // 16 MB (reused as ctx after QKV)
    u16* Wqk_t = (u16*)(ws + 16777216);    // 1 MB  (512,1024) = [wq^T ; wk^T]
    u16* Wv_t  = (u16*)(ws + 17825792);    // 2 MB  (1024,1024)
    u16* Wo_t  = (u16*)(ws + 19922944);    // 2 MB
    u16* W1_t  = (u16*)(ws + 22020096);    // 0.5 MB (256,1024)
    u16* W2_t  = (u16*)(ws + 22544384);    // 0.5 MB (1024,256)
    u16* QKb   = (u16*)(ws + 23068672);    // 8 MB  (8192,512) (reused as h)
    u16* Vt    = (u16*)(ws + 31457280);    // 16 MB (1024,8192)  V^T
    u16* attnb = (u16*)(ws + 48234496);    // 32 MB (4,2048,2048) bf16
    float* res_f = (float*)(ws + 81788928);// 32 MB (8192,1024) fp32
    u16* res_b = (u16*)(ws + 115343360);   // 16 MB residual bf16
    u16* ctxb = Xb;                        // alias: X dead after QKV GEMMs
    u16* hb   = QKb;                       // alias: QK dead after scores GEMM

    dim3 blk(256);

    // 1. prep: X->bf16 + all weight transposes (one launch)
    prep_kernel<<<dim3(4096), blk, 0, stream>>>(x, Xb, wq, wk, Wqk_t, wv, Wv_t,
                                                wo, Wo_t, w1, W1_t, w2, W2_t);
    // 2. [Q|K] = X @ [wq|wk]  (8192,512)  +  V^T = Wv^T @ X^T (1024,8192), merged
    gemm_qkv<<<dim3(768), blk, 0, stream>>>(Xb, Wqk_t, QKb, Wv_t, Vt);
    // 3. scores = Q @ K^T * 1/16  -> fp32 into d_out attn region (per batch)
    gemm_bt<2><<<dim3(1024), blk, 0, stream>>>(
        QKb, (long)2048 * 512, 512, QKb + 256, (long)2048 * 512, 512,
        (u16*)nullptr, 0L, 0, attn_f, (long)2048 * 2048, 2048,
        256, 0.0625f, (const float*)nullptr, (const float*)nullptr, 0L, 16, 16);
    // 4. softmax rows (in-place fp32 + bf16 copy)
    softmax_kernel<<<dim3(8192), blk, 0, stream>>>(attn_f, attnb);
    // 5. context = attn @ V  (per batch; B = V^T slice)
    gemm_bt<0><<<dim3(512), blk, 0, stream>>>(
        attnb, (long)2048 * 2048, 2048, Vt, 2048L, 8192,
        ctxb, (long)2048 * 1024, 1024, (float*)nullptr, 0L, 0,
        2048, 1.0f, (const float*)nullptr, (const float*)nullptr, 0L, 8, 16);
    // 6. residual = x + context @ wo + bo  (fp32 + bf16)
    gemm_bt<4><<<dim3(512), blk, 0, stream>>>(
        ctxb, 0L, 1024, Wo_t, 0L, 1024, res_b, 0L, 1024,
        res_f, 0L, 1024, 1024, 1.0f, bo, x, 0L, 8, 64);
    // 7. h = relu(residual @ w1 + b1)  (8192,256)
    gemm_bt<3><<<dim3(128), blk, 0, stream>>>(
        res_b, 0L, 1024, W1_t, 0L, 1024, hb, 0L, 256,
        (float*)nullptr, 0L, 0, 1024, 1.0f, b1, (const float*)nullptr, 0L, 2, 64);
    // 8. out = residual + h @ w2 + b2  (fp32, first output)
    gemm_bt<5><<<dim3(512), blk, 0, stream>>>(
        hb, 0L, 256, W2_t, 0L, 256, (u16*)nullptr, 0L, 0,
        out_f, 0L, 1024, 256, 1.0f, b2, res_f, 0L, 8, 64);
}

// Round 3
// 231.951 us; speedup vs baseline: 1.9719x; 1.9719x over previous
//
#include <hip/hip_runtime.h>

typedef unsigned short u16;
typedef unsigned int u32;
typedef __bf16 bf16x8 __attribute__((ext_vector_type(8)));
typedef float f32x4 __attribute__((ext_vector_type(4)));

#define MTOT 8192
#define DM 1024
#define DI 256
#define TT 2048

__device__ __forceinline__ u16 f2bf(float f) {
    u32 u = __float_as_uint(f);
    return (u16)((u + 0x7fffu + ((u >> 16) & 1u)) >> 16);
}

// ================= prep: X cvt + 6 weight transposes in ONE launch =================
__device__ __forceinline__ void transpose_tile(const float* __restrict__ in,
                                               u16* __restrict__ out, int K, int N,
                                               int bx, int by) {
    __shared__ float t[32][33];
    int n0 = bx * 32, k0 = by * 32;
    int tx = threadIdx.x & 31, ty = threadIdx.x >> 5;
    #pragma unroll
    for (int i = ty; i < 32; i += 8) t[i][tx] = in[(long)(k0 + i) * N + n0 + tx];
    __syncthreads();
    #pragma unroll
    for (int i = ty; i < 32; i += 8) out[(long)(n0 + i) * K + k0 + tx] = f2bf(t[tx][i]);
}

__global__ __launch_bounds__(256) void prep_kernel(
    const float* __restrict__ x, u16* __restrict__ Xb,
    const float* __restrict__ wq, const float* __restrict__ wk, u16* __restrict__ Wqk_t,
    const float* __restrict__ wv, u16* __restrict__ Wv_t,
    const float* __restrict__ wo, u16* __restrict__ Wo_t,
    const float* __restrict__ w1, u16* __restrict__ W1_t,
    const float* __restrict__ w2, u16* __restrict__ W2_t)
{
    int b = blockIdx.x;
    if (b < 1024) {
        long n4 = (long)MTOT * DM / 4;
        long i = (long)b * 256 + threadIdx.x;
        long stride = 1024L * 256;
        for (; i < n4; i += stride) {
            float4 v = reinterpret_cast<const float4*>(x)[i];
            union { u16 u[4]; uint2 p; } o;
            o.u[0] = f2bf(v.x); o.u[1] = f2bf(v.y); o.u[2] = f2bf(v.z); o.u[3] = f2bf(v.w);
            reinterpret_cast<uint2*>(Xb)[i] = o.p;
        }
        return;
    }
    b -= 1024;
    if (b < 256)        { transpose_tile(wq, Wqk_t,              1024,  256, b & 7,  b >> 3); return; }
    b -= 256;
    if (b < 256)        { transpose_tile(wk, Wqk_t + 256 * 1024, 1024,  256, b & 7,  b >> 3); return; }
    b -= 256;
    if (b < 1024)       { transpose_tile(wv, Wv_t,               1024, 1024, b & 31, b >> 5); return; }
    b -= 1024;
    if (b < 1024)       { transpose_tile(wo, Wo_t,               1024, 1024, b & 31, b >> 5); return; }
    b -= 1024;
    if (b < 256)        { transpose_tile(w1, W1_t,               1024,  256, b & 7,  b >> 3); return; }
    b -= 256;
    /* w2: (256,1024) -> (1024,256): tiles 32 x 8 */
    transpose_tile(w2, W2_t, 256, 1024, b & 31, b >> 5);
}

// ---------------- row softmax over T=2048, in-place fp32 + bf16 copy ----------------
__global__ __launch_bounds__(256) void softmax_kernel(float* __restrict__ S, u16* __restrict__ Sb) {
    long row = blockIdx.x;
    float* p = S + row * (long)TT;
    int tid = threadIdx.x;
    float4 v0 = reinterpret_cast<float4*>(p)[tid * 2];
    float4 v1 = reinterpret_cast<float4*>(p)[tid * 2 + 1];
    float vv[8] = {v0.x, v0.y, v0.z, v0.w, v1.x, v1.y, v1.z, v1.w};
    float m = vv[0];
    #pragma unroll
    for (int j = 1; j < 8; ++j) m = fmaxf(m, vv[j]);
    #pragma unroll
    for (int off = 32; off; off >>= 1) m = fmaxf(m, __shfl_xor(m, off));
    __shared__ float redm[4], reds[4];
    if ((tid & 63) == 0) redm[tid >> 6] = m;
    __syncthreads();
    m = fmaxf(fmaxf(redm[0], redm[1]), fmaxf(redm[2], redm[3]));
    float s = 0.f;
    #pragma unroll
    for (int j = 0; j < 8; ++j) { vv[j] = __expf(vv[j] - m); s += vv[j]; }
    #pragma unroll
    for (int off = 32; off; off >>= 1) s += __shfl_xor(s, off);
    if ((tid & 63) == 0) reds[tid >> 6] = s;
    __syncthreads();
    s = reds[0] + reds[1] + reds[2] + reds[3];
    float inv = 1.0f / s;
    #pragma unroll
    for (int j = 0; j < 8; ++j) vv[j] *= inv;
    reinterpret_cast<float4*>(p)[tid * 2]     = make_float4(vv[0], vv[1], vv[2], vv[3]);
    reinterpret_cast<float4*>(p)[tid * 2 + 1] = make_float4(vv[4], vv[5], vv[6], vv[7]);
    union { u16 u[8]; uint4 q; } pk;
    #pragma unroll
    for (int j = 0; j < 8; ++j) pk.u[j] = f2bf(vv[j]);
    reinterpret_cast<uint4*>(Sb + row * (long)TT)[tid] = pk.q;
}

// ---------------- GEMM body: C = A (M,K) @ Bt^T, Bt stored (N,K). ----------------
// m97 structure: 128x128 tile, BK=64, 4 waves, global_load_lds(16B),
// XOR-swizzle (linear LDS dest + pre-swizzled global source + swizzled ds_read).
// MODE: 0 = bf16 C            1 = bf16 C^T (transposed store)
//       2 = fp32 C * scale    3 = bf16 relu(C + bias)
//       4 = Cf = addend + C + bias, Cb = bf16(Cf)
//       5 = Cf = addend + C + bias
template<int MODE>
__device__ __forceinline__ void gemm_body(
    u16* As, u16* Bs,
    const u16* __restrict__ A, int lda,
    const u16* __restrict__ Bt, int ldb,
    u16* __restrict__ Cb, int ldcb,
    float* __restrict__ Cf, int ldcf,
    int K, float scale,
    const float* __restrict__ bias,
    const float* __restrict__ addend,
    long tile_m, long tile_n)
{
    const int tid = threadIdx.x;
    const int w = tid >> 6;
    const int l = tid & 63;
    const int lane15 = l & 15;
    const int lhi = l >> 4;

    // staging: each issue i covers 32 rows; lane l -> row w*8 + (l>>3) within the
    // 32-row chunk, 16B chunk (l&7) XOR-swizzled by row&7 (= l>>3).
    const int srow = w * 8 + (l >> 3);
    const int scol = (((l & 7) ^ (l >> 3)) << 4) >> 1; // element offset in row

    const u16* aptr = A + (tile_m + srow) * (long)lda + scol;
    const u16* bptr = Bt + (tile_n + srow) * (long)ldb + scol;

    f32x4 acc[4][4] = {};

    const int wr = (w >> 1) * 64;
    const int wc = (w & 1) * 64;

    for (int k0 = 0; k0 < K; k0 += 64) {
        #pragma unroll
        for (int i = 0; i < 4; ++i) {
            __builtin_amdgcn_global_load_lds(
                (const __attribute__((address_space(1))) void*)(aptr + (long)i * 32 * lda + k0),
                (__attribute__((address_space(3))) void*)((char*)As + i * 4096 + w * 1024),
                16, 0, 0);
        }
        #pragma unroll
        for (int i = 0; i < 4; ++i) {
            __builtin_amdgcn_global_load_lds(
                (const __attribute__((address_space(1))) void*)(bptr + (long)i * 32 * ldb + k0),
                (__attribute__((address_space(3))) void*)((char*)Bs + i * 4096 + w * 1024),
                16, 0, 0);
        }
        __syncthreads();
        #pragma unroll
        for (int kk = 0; kk < 2; ++kk) {
            bf16x8 af[4], bfr[4];
            const int kb = (kk * 32 + lhi * 8) * 2; // byte offset of k within row
            #pragma unroll
            for (int m = 0; m < 4; ++m) {
                int r = wr + m * 16 + lane15;
                af[m] = *reinterpret_cast<const bf16x8*>(
                    (const char*)As + r * 128 + (kb ^ ((r & 7) << 4)));
            }
            #pragma unroll
            for (int n = 0; n < 4; ++n) {
                int r = wc + n * 16 + lane15;
                bfr[n] = *reinterpret_cast<const bf16x8*>(
                    (const char*)Bs + r * 128 + (kb ^ ((r & 7) << 4)));
            }
            #pragma unroll
            for (int m = 0; m < 4; ++m)
                #pragma unroll
                for (int n = 0; n < 4; ++n)
                    acc[m][n] = __builtin_amdgcn_mfma_f32_16x16x32_bf16(
                        af[m], bfr[n], acc[m][n], 0, 0, 0);
        }
        __syncthreads();
    }

    // epilogue: C/D layout col = lane&15, row = (lane>>4)*4 + reg (m89-verified)
    #pragma unroll
    for (int m = 0; m < 4; ++m) {
        #pragma unroll
        for (int n = 0; n < 4; ++n) {
            long grow0 = tile_m + wr + m * 16 + lhi * 4;
            long gcol  = tile_n + wc + n * 16 + lane15;
            #pragma unroll
            for (int r = 0; r < 4; ++r) {
                long grow = grow0 + r;
                float v = acc[m][n][r];
                if (MODE == 2) v *= scale;
                if (MODE == 3 || MODE == 4 || MODE == 5) v += bias[gcol];
                if (MODE == 4 || MODE == 5) v += addend[grow * (long)ldcf + gcol];
                if (MODE == 3) v = fmaxf(v, 0.0f);
                if (MODE == 0 || MODE == 3 || MODE == 4) Cb[grow * (long)ldcb + gcol] = f2bf(v);
                if (MODE == 1) Cb[gcol * (long)ldcb + grow] = f2bf(v);
                if (MODE == 2 || MODE == 4 || MODE == 5) Cf[grow * (long)ldcf + gcol] = v;
            }
        }
    }
}

// XCD-chunked bijective swizzle (valid because all grids are %8==0):
// hardware round-robins bid across 8 XCDs; logical id (bid&7)*cpx + bid>>3
// gives XCD j the contiguous logical chunk [j*cpx, (j+1)*cpx).
__device__ __forceinline__ int xcd_swizzle(int bid, int nb) {
    return (bid & 7) * (nb >> 3) + (bid >> 3);
}

template<int MODE>
__global__ __launch_bounds__(256) void gemm_bt(
    const u16* __restrict__ A, long sA, int lda,
    const u16* __restrict__ Bt, long sB, int ldb,
    u16* __restrict__ Cb, long sCb, int ldcb,
    float* __restrict__ Cf, long sCf, int ldcf,
    int K, float scale,
    const float* __restrict__ bias,
    const float* __restrict__ addend, long sAdd,
    int gx, int gy)
{
    __shared__ __attribute__((aligned(16))) u16 As[128 * 64];
    __shared__ __attribute__((aligned(16))) u16 Bs[128 * 64];

    int lid = xcd_swizzle(blockIdx.x, gridDim.x);
    int x = lid % gx;
    int t = lid / gx;
    int y = t % gy;
    int z = t / gy;

    gemm_body<MODE>(As, Bs,
                    A + (long)z * sA, lda, Bt + (long)z * sB, ldb,
                    Cb + (long)z * sCb, ldcb, Cf + (long)z * sCf, ldcf,
                    K, scale, bias,
                    addend ? addend + (long)z * sAdd : addend,
                    (long)y * 128, (long)x * 128);
}

extern "C" void kernel_launch(void* const* d_in, const int* in_sizes, int n_in,
                              void* d_out, int out_size, void* d_ws, size_t ws_size,
                              hipStream_t stream)
{
    const float* x  = (const float*)d_in[0];
    const float* wq = (const float*)d_in[1];
    const float* wk = (const float*)d_in[2];
    const float* wv = (const float*)d_in[3];
    const float* wo = (const float*)d_in[4];
    const float* bo = (const float*)d_in[5];
    const float* w1 = (const float*)d_in[6];
    const float* b1 = (const float*)d_in[7];
    const float* w2 = (const float*)d_in[8];
    const float* b2 = (const float*)d_in[9];

    float* out_f  = (float*)d_out;
    float* attn_f = out_f + (long)MTOT * DM;  // second output, (4,2048,2048) fp32

    char* ws = (char*)d_ws;
    u16* Xb    = (u16*)(ws + 0);           // 16 MB (reused as ctx after QKV)
    u16* Wqk_t = (u16*)(ws + 16777216);    // 1 MB  (512,1024) = [wq^T ; wk^T]
    u16* Wv_t  = (u16*)(ws + 17825792);    // 2 MB  (1024,1024)
    u16* Wo_t  = (u16*)(ws + 19922944);    // 2 MB
    u16* W1_t  = (u16*)(ws + 22020096);    // 0.5 MB (256,1024)
    u16* W2_t  = (u16*)(ws + 22544384);    // 0.5 MB (1024,256)
    u16* QKb   = (u16*)(ws + 23068672);    // 8 MB  (8192,512) (reused as h)
    u16* Vt    = (u16*)(ws + 31457280);    // 16 MB (1024,8192)  V^T
    u16* attnb = (u16*)(ws + 48234496);    // 32 MB (4,2048,2048) bf16
    float* res_f = (float*)(ws + 81788928);// 32 MB (8192,1024) fp32
    u16* res_b = (u16*)(ws + 115343360);   // 16 MB residual bf16
    u16* ctxb = Xb;                        // alias: X dead after QKV GEMMs
    u16* hb   = QKb;                       // alias: QK dead after scores GEMM

    dim3 blk(256);

    // 1. prep: X->bf16 + all weight transposes (one launch)
    prep_kernel<<<dim3(4096), blk, 0, stream>>>(x, Xb, wq, wk, Wqk_t, wv, Wv_t,
                                                wo, Wo_t, w1, W1_t, w2, W2_t);
    // 2a. [Q|K] = X @ [wq|wk]  (8192,512)
    gemm_bt<0><<<dim3(256), blk, 0, stream>>>(
        Xb, 0L, 1024, Wqk_t, 0L, 1024, QKb, 0L, 512,
        (float*)nullptr, 0L, 0, 1024, 1.0f, (const float*)nullptr,
        (const float*)nullptr, 0L, 4, 64);
    // 2b. V^T = (X @ wv)^T  (1024,8192) — X as A operand (L2-friendly),
    //     transposed store. gx=8 keeps one Wv panel pinned per XCD.
    gemm_bt<1><<<dim3(512), blk, 0, stream>>>(
        Xb, 0L, 1024, Wv_t, 0L, 1024, Vt, 0L, 8192,
        (float*)nullptr, 0L, 0, 1024, 1.0f, (const float*)nullptr,
        (const float*)nullptr, 0L, 8, 64);
    // 3. scores = Q @ K^T * 1/16  -> fp32 into d_out attn region (per batch)
    gemm_bt<2><<<dim3(1024), blk, 0, stream>>>(
        QKb, (long)2048 * 512, 512, QKb + 256, (long)2048 * 512, 512,
        (u16*)nullptr, 0L, 0, attn_f, (long)2048 * 2048, 2048,
        256, 0.0625f, (const float*)nullptr, (const float*)nullptr, 0L, 16, 16);
    // 4. softmax rows (in-place fp32 + bf16 copy)
    softmax_kernel<<<dim3(8192), blk, 0, stream>>>(attn_f, attnb);
    // 5. context = attn @ V  (per batch; B = V^T slice)
    gemm_bt<0><<<dim3(512), blk, 0, stream>>>(
        attnb, (long)2048 * 2048, 2048, Vt, 2048L, 8192,
        ctxb, (long)2048 * 1024, 1024, (float*)nullptr, 0L, 0,
        2048, 1.0f, (const float*)nullptr, (const float*)nullptr, 0L, 8, 16);
    // 6. residual = x + context @ wo + bo  (fp32 + bf16)
    gemm_bt<4><<<dim3(512), blk, 0, stream>>>(
        ctxb, 0L, 1024, Wo_t, 0L, 1024, res_b, 0L, 1024,
        res_f, 0L, 1024, 1024, 1.0f, bo, x, 0L, 8, 64);
    // 7. h = relu(residual @ w1 + b1)  (8192,256)
    gemm_bt<3><<<dim3(128), blk, 0, stream>>>(
        res_b, 0L, 1024, W1_t, 0L, 1024, hb, 0L, 256,
        (float*)nullptr, 0L, 0, 1024, 1.0f, b1, (const float*)nullptr, 0L, 2, 64);
    // 8. out = residual + h @ w2 + b2  (fp32, first output)
    gemm_bt<5><<<dim3(512), blk, 0, stream>>>(
        hb, 0L, 256, W2_t, 0L, 256, (u16*)nullptr, 0L, 0,
        out_f, 0L, 1024, 256, 1.0f, b2, res_f, 0L, 8, 64);
}

// Round 4
// 203.782 us; speedup vs baseline: 2.2445x; 1.1382x over previous
//
#include <hip/hip_runtime.h>

typedef unsigned short u16;
typedef unsigned int u32;
typedef __bf16 bf16x8 __attribute__((ext_vector_type(8)));
typedef float f32x4 __attribute__((ext_vector_type(4)));

#define MTOT 8192
#define DM 1024
#define DI 256
#define TT 2048

__device__ __forceinline__ u16 f2bf(float f) {
    u32 u = __float_as_uint(f);
    return (u16)((u + 0x7fffu + ((u >> 16) & 1u)) >> 16);
}
__device__ __forceinline__ float b2f(u16 b) {
    return __uint_as_float((u32)b << 16);
}

// ================= prep: X cvt + 6 weight transposes in ONE launch =================
__device__ __forceinline__ void transpose_tile(const float* __restrict__ in,
                                               u16* __restrict__ out, int K, int N,
                                               int bx, int by) {
    __shared__ float t[32][33];
    int n0 = bx * 32, k0 = by * 32;
    int tx = threadIdx.x & 31, ty = threadIdx.x >> 5;
    #pragma unroll
    for (int i = ty; i < 32; i += 8) t[i][tx] = in[(long)(k0 + i) * N + n0 + tx];
    __syncthreads();
    #pragma unroll
    for (int i = ty; i < 32; i += 8) out[(long)(n0 + i) * K + k0 + tx] = f2bf(t[tx][i]);
}

__global__ __launch_bounds__(256) void prep_kernel(
    const float* __restrict__ x, u16* __restrict__ Xb,
    const float* __restrict__ wq, const float* __restrict__ wk, u16* __restrict__ Wqk_t,
    const float* __restrict__ wv, u16* __restrict__ Wv_t,
    const float* __restrict__ wo, u16* __restrict__ Wo_t,
    const float* __restrict__ w1, u16* __restrict__ W1_t,
    const float* __restrict__ w2, u16* __restrict__ W2_t)
{
    int b = blockIdx.x;
    if (b < 1024) {
        long n4 = (long)MTOT * DM / 4;
        long i = (long)b * 256 + threadIdx.x;
        long stride = 1024L * 256;
        for (; i < n4; i += stride) {
            float4 v = reinterpret_cast<const float4*>(x)[i];
            union { u16 u[4]; uint2 p; } o;
            o.u[0] = f2bf(v.x); o.u[1] = f2bf(v.y); o.u[2] = f2bf(v.z); o.u[3] = f2bf(v.w);
            reinterpret_cast<uint2*>(Xb)[i] = o.p;
        }
        return;
    }
    b -= 1024;
    if (b < 256)        { transpose_tile(wq, Wqk_t,              1024,  256, b & 7,  b >> 3); return; }
    b -= 256;
    if (b < 256)        { transpose_tile(wk, Wqk_t + 256 * 1024, 1024,  256, b & 7,  b >> 3); return; }
    b -= 256;
    if (b < 1024)       { transpose_tile(wv, Wv_t,               1024, 1024, b & 31, b >> 5); return; }
    b -= 1024;
    if (b < 1024)       { transpose_tile(wo, Wo_t,               1024, 1024, b & 31, b >> 5); return; }
    b -= 1024;
    if (b < 256)        { transpose_tile(w1, W1_t,               1024,  256, b & 7,  b >> 3); return; }
    b -= 256;
    /* w2: (256,1024) -> (1024,256): tiles 32 x 8 */
    transpose_tile(w2, W2_t, 256, 1024, b & 31, b >> 5);
}

// ------- row softmax over T=2048: read raw bf16 scores, write fp32 attn + bf16 in place -------
__global__ __launch_bounds__(256) void softmax_kernel(u16* __restrict__ Sb, float* __restrict__ attn) {
    long row = blockIdx.x;
    int tid = threadIdx.x;
    uint4 q = reinterpret_cast<uint4*>(Sb + row * (long)TT)[tid];
    u32 w4[4] = {q.x, q.y, q.z, q.w};
    float vv[8];
    #pragma unroll
    for (int j = 0; j < 4; ++j) {
        vv[2 * j]     = __uint_as_float(w4[j] << 16);
        vv[2 * j + 1] = __uint_as_float(w4[j] & 0xffff0000u);
    }
    float m = vv[0];
    #pragma unroll
    for (int j = 1; j < 8; ++j) m = fmaxf(m, vv[j]);
    #pragma unroll
    for (int off = 32; off; off >>= 1) m = fmaxf(m, __shfl_xor(m, off));
    __shared__ float redm[4], reds[4];
    if ((tid & 63) == 0) redm[tid >> 6] = m;
    __syncthreads();
    m = fmaxf(fmaxf(redm[0], redm[1]), fmaxf(redm[2], redm[3]));
    float s = 0.f;
    #pragma unroll
    for (int j = 0; j < 8; ++j) { vv[j] = __expf(vv[j] - m); s += vv[j]; }
    #pragma unroll
    for (int off = 32; off; off >>= 1) s += __shfl_xor(s, off);
    if ((tid & 63) == 0) reds[tid >> 6] = s;
    __syncthreads();
    s = reds[0] + reds[1] + reds[2] + reds[3];
    float inv = 1.0f / s;
    #pragma unroll
    for (int j = 0; j < 8; ++j) vv[j] *= inv;
    float* p = attn + row * (long)TT;
    reinterpret_cast<float4*>(p)[tid * 2]     = make_float4(vv[0], vv[1], vv[2], vv[3]);
    reinterpret_cast<float4*>(p)[tid * 2 + 1] = make_float4(vv[4], vv[5], vv[6], vv[7]);
    union { u16 u[8]; uint4 q; } pk;
    #pragma unroll
    for (int j = 0; j < 8; ++j) pk.u[j] = f2bf(vv[j]);
    reinterpret_cast<uint4*>(Sb + row * (long)TT)[tid] = pk.q;
}

// ---------------- GEMM body: C = A (M,K) @ Bt^T, Bt stored (N,K). ----------------
// m97 structure: 128x128 tile, BK=64, 4 waves, global_load_lds(16B),
// XOR-swizzle (linear LDS dest + pre-swizzled global source + swizzled ds_read).
// MODE: 0 = bf16 C * scale    1 = bf16 C^T (transposed store)
//       3 = bf16 relu(C + bias)
//       6 = bf16 (C + bias + bf16_addend)      (Wo: residual, bf16 out only)
//       7 = fp32 (C + bias + bf16_addend)      (FFN2: final out)
template<int MODE>
__device__ __forceinline__ void gemm_body(
    u16* As, u16* Bs,
    const u16* __restrict__ A, int lda,
    const u16* __restrict__ Bt, int ldb,
    u16* __restrict__ Cb, int ldcb,
    float* __restrict__ Cf, int ldcf,
    int K, float scale,
    const float* __restrict__ bias,
    const u16* __restrict__ addend_b, int ld_add,
    long tile_m, long tile_n)
{
    const int tid = threadIdx.x;
    const int w = tid >> 6;
    const int l = tid & 63;
    const int lane15 = l & 15;
    const int lhi = l >> 4;

    // staging: each issue i covers 32 rows; lane l -> row w*8 + (l>>3) within the
    // 32-row chunk, 16B chunk (l&7) XOR-swizzled by row&7 (= l>>3).
    const int srow = w * 8 + (l >> 3);
    const int scol = (((l & 7) ^ (l >> 3)) << 4) >> 1; // element offset in row

    const u16* aptr = A + (tile_m + srow) * (long)lda + scol;
    const u16* bptr = Bt + (tile_n + srow) * (long)ldb + scol;

    f32x4 acc[4][4] = {};

    const int wr = (w >> 1) * 64;
    const int wc = (w & 1) * 64;

    for (int k0 = 0; k0 < K; k0 += 64) {
        #pragma unroll
        for (int i = 0; i < 4; ++i) {
            __builtin_amdgcn_global_load_lds(
                (const __attribute__((address_space(1))) void*)(aptr + (long)i * 32 * lda + k0),
                (__attribute__((address_space(3))) void*)((char*)As + i * 4096 + w * 1024),
                16, 0, 0);
        }
        #pragma unroll
        for (int i = 0; i < 4; ++i) {
            __builtin_amdgcn_global_load_lds(
                (const __attribute__((address_space(1))) void*)(bptr + (long)i * 32 * ldb + k0),
                (__attribute__((address_space(3))) void*)((char*)Bs + i * 4096 + w * 1024),
                16, 0, 0);
        }
        __syncthreads();
        #pragma unroll
        for (int kk = 0; kk < 2; ++kk) {
            bf16x8 af[4], bfr[4];
            const int kb = (kk * 32 + lhi * 8) * 2; // byte offset of k within row
            #pragma unroll
            for (int m = 0; m < 4; ++m) {
                int r = wr + m * 16 + lane15;
                af[m] = *reinterpret_cast<const bf16x8*>(
                    (const char*)As + r * 128 + (kb ^ ((r & 7) << 4)));
            }
            #pragma unroll
            for (int n = 0; n < 4; ++n) {
                int r = wc + n * 16 + lane15;
                bfr[n] = *reinterpret_cast<const bf16x8*>(
                    (const char*)Bs + r * 128 + (kb ^ ((r & 7) << 4)));
            }
            #pragma unroll
            for (int m = 0; m < 4; ++m)
                #pragma unroll
                for (int n = 0; n < 4; ++n)
                    acc[m][n] = __builtin_amdgcn_mfma_f32_16x16x32_bf16(
                        af[m], bfr[n], acc[m][n], 0, 0, 0);
        }
        __syncthreads();
    }

    // epilogue: C/D layout col = lane&15, row = (lane>>4)*4 + reg (m89-verified)
    #pragma unroll
    for (int m = 0; m < 4; ++m) {
        #pragma unroll
        for (int n = 0; n < 4; ++n) {
            long grow0 = tile_m + wr + m * 16 + lhi * 4;
            long gcol  = tile_n + wc + n * 16 + lane15;
            #pragma unroll
            for (int r = 0; r < 4; ++r) {
                long grow = grow0 + r;
                float v = acc[m][n][r];
                if (MODE == 0) v *= scale;
                if (MODE == 3 || MODE == 6 || MODE == 7) v += bias[gcol];
                if (MODE == 6 || MODE == 7) v += b2f(addend_b[grow * (long)ld_add + gcol]);
                if (MODE == 3) v = fmaxf(v, 0.0f);
                if (MODE == 0 || MODE == 3 || MODE == 6) Cb[grow * (long)ldcb + gcol] = f2bf(v);
                if (MODE == 1) Cb[gcol * (long)ldcb + grow] = f2bf(v);
                if (MODE == 7) Cf[grow * (long)ldcf + gcol] = v;
            }
        }
    }
}

// XCD-chunked bijective swizzle (valid because all grids are %8==0):
// hardware round-robins bid across 8 XCDs; logical id (bid&7)*cpx + bid>>3
// gives XCD j the contiguous logical chunk [j*cpx, (j+1)*cpx).
__device__ __forceinline__ int xcd_swizzle(int bid, int nb) {
    return (bid & 7) * (nb >> 3) + (bid >> 3);
}

template<int MODE>
__global__ __launch_bounds__(256) void gemm_bt(
    const u16* __restrict__ A, long sA, int lda,
    const u16* __restrict__ Bt, long sB, int ldb,
    u16* __restrict__ Cb, long sCb, int ldcb,
    float* __restrict__ Cf, long sCf, int ldcf,
    int K, float scale,
    const float* __restrict__ bias,
    const u16* __restrict__ addend_b, long sAdd, int ld_add,
    int gx, int gy)
{
    __shared__ __attribute__((aligned(16))) u16 As[128 * 64];
    __shared__ __attribute__((aligned(16))) u16 Bs[128 * 64];

    int lid = xcd_swizzle(blockIdx.x, gridDim.x);
    int x = lid % gx;
    int t = lid / gx;
    int y = t % gy;
    int z = t / gy;

    gemm_body<MODE>(As, Bs,
                    A + (long)z * sA, lda, Bt + (long)z * sB, ldb,
                    Cb + (long)z * sCb, ldcb, Cf + (long)z * sCf, ldcf,
                    K, scale, bias,
                    addend_b ? addend_b + (long)z * sAdd : addend_b, ld_add,
                    (long)y * 128, (long)x * 128);
}

// Merged QK + V^T dispatch (both consume Xb as the A operand; independent outputs):
// logical ids [0,256):   QK = Xb @ Wqk_t^T (8192,512), gx=4, gy=64  (mode 0)
// logical ids [256,768): V^T = (Xb @ Wv_t^T)^T -> (1024,8192), gx=8, gy=64 (mode 1)
__global__ __launch_bounds__(256) void gemm_qkv(
    const u16* __restrict__ Xb, const u16* __restrict__ Wqk_t, u16* __restrict__ QKb,
    const u16* __restrict__ Wv_t, u16* __restrict__ Vt)
{
    __shared__ __attribute__((aligned(16))) u16 As[128 * 64];
    __shared__ __attribute__((aligned(16))) u16 Bs[128 * 64];

    int lid = xcd_swizzle(blockIdx.x, gridDim.x);
    if (lid < 256) {
        int x = lid & 3, y = lid >> 2;
        gemm_body<0>(As, Bs, Xb, 1024, Wqk_t, 1024, QKb, 512,
                     (float*)nullptr, 0, 1024, 1.0f,
                     (const float*)nullptr, (const u16*)nullptr, 0,
                     (long)y * 128, (long)x * 128);
    } else {
        int l2 = lid - 256;
        int x = l2 & 7, y = l2 >> 3;
        gemm_body<1>(As, Bs, Xb, 1024, Wv_t, 1024, Vt, 8192,
                     (float*)nullptr, 0, 1024, 1.0f,
                     (const float*)nullptr, (const u16*)nullptr, 0,
                     (long)y * 128, (long)x * 128);
    }
}

extern "C" void kernel_launch(void* const* d_in, const int* in_sizes, int n_in,
                              void* d_out, int out_size, void* d_ws, size_t ws_size,
                              hipStream_t stream)
{
    const float* x  = (const float*)d_in[0];
    const float* wq = (const float*)d_in[1];
    const float* wk = (const float*)d_in[2];
    const float* wv = (const float*)d_in[3];
    const float* wo = (const float*)d_in[4];
    const float* bo = (const float*)d_in[5];
    const float* w1 = (const float*)d_in[6];
    const float* b1 = (const float*)d_in[7];
    const float* w2 = (const float*)d_in[8];
    const float* b2 = (const float*)d_in[9];

    float* out_f  = (float*)d_out;
    float* attn_f = out_f + (long)MTOT * DM;  // second output, (4,2048,2048) fp32

    char* ws = (char*)d_ws;
    u16* Xb    = (u16*)(ws + 0);            // 16 MB bf16 X (also Wo residual addend)
    u16* Wqk_t = (u16*)(ws + 16777216);     // 1 MB  (512,1024) = [wq^T ; wk^T]
    u16* Wv_t  = (u16*)(ws + 17825792);     // 2 MB  (1024,1024)
    u16* Wo_t  = (u16*)(ws + 19922944);     // 2 MB
    u16* W1_t  = (u16*)(ws + 22020096);     // 0.5 MB (256,1024)
    u16* W2_t  = (u16*)(ws + 22544384);     // 0.5 MB (1024,256)
    u16* QKb   = (u16*)(ws + 23068672);     // 8 MB  (8192,512) (reused as h)
    u16* Vt    = (u16*)(ws + 31457280);     // 16 MB (1024,8192)  V^T
    u16* attnb = (u16*)(ws + 48234496);     // 32 MB (4,2048,2048) bf16: raw scores -> attn
    u16* ctxb  = (u16*)(ws + 81788928);     // 16 MB (8192,1024) context bf16
    u16* res_b = (u16*)(ws + 98566144);     // 16 MB residual bf16
    u16* hb    = QKb;                       // alias: QK dead after scores GEMM

    dim3 blk(256);

    // 1. prep: X->bf16 + all weight transposes (one launch)
    prep_kernel<<<dim3(4096), blk, 0, stream>>>(x, Xb, wq, wk, Wqk_t, wv, Wv_t,
                                                wo, Wo_t, w1, W1_t, w2, W2_t);
    // 2. merged QK (mode 0) + V^T (mode 1)
    gemm_qkv<<<dim3(768), blk, 0, stream>>>(Xb, Wqk_t, QKb, Wv_t, Vt);
    // 3. raw scores (bf16) = Q @ K^T * 1/16 -> attnb
    gemm_bt<0><<<dim3(1024), blk, 0, stream>>>(
        QKb, (long)2048 * 512, 512, QKb + 256, (long)2048 * 512, 512,
        attnb, (long)2048 * 2048, 2048, (float*)nullptr, 0L, 0,
        256, 0.0625f, (const float*)nullptr, (const u16*)nullptr, 0L, 0, 16, 16);
    // 4. softmax: attnb (raw bf16) -> attn_f fp32 (output) + attnb bf16 (in place)
    softmax_kernel<<<dim3(8192), blk, 0, stream>>>(attnb, attn_f);
    // 5. context = attn @ V  (per batch; B = V^T slice)
    gemm_bt<0><<<dim3(512), blk, 0, stream>>>(
        attnb, (long)2048 * 2048, 2048, Vt, 2048L, 8192,
        ctxb, (long)2048 * 1024, 1024, (float*)nullptr, 0L, 0,
        2048, 1.0f, (const float*)nullptr, (const u16*)nullptr, 0L, 0, 8, 16);
    // 6. residual(bf16) = bf16(Xb + context @ wo + bo)
    gemm_bt<6><<<dim3(512), blk, 0, stream>>>(
        ctxb, 0L, 1024, Wo_t, 0L, 1024, res_b, 0L, 1024,
        (float*)nullptr, 0L, 0, 1024, 1.0f, bo, Xb, 0L, 1024, 8, 64);
    // 7. h = relu(residual @ w1 + b1)  (8192,256)
    gemm_bt<3><<<dim3(128), blk, 0, stream>>>(
        res_b, 0L, 1024, W1_t, 0L, 1024, hb, 0L, 256,
        (float*)nullptr, 0L, 0, 1024, 1.0f, b1, (const u16*)nullptr, 0L, 0, 2, 64);
    // 8. out = residual + h @ w2 + b2  (fp32, first output)
    gemm_bt<7><<<dim3(512), blk, 0, stream>>>(
        hb, 0L, 256, W2_t, 0L, 256, (u16*)nullptr, 0L, 0,
        out_f, 0L, 1024, 256, 1.0f, b2, res_b, 0L, 1024, 8, 64);
}

// Round 5
// 197.714 us; speedup vs baseline: 2.3134x; 1.0307x over previous
//
#include <hip/hip_runtime.h>

typedef unsigned short u16;
typedef unsigned int u32;
typedef __bf16 bf16x8 __attribute__((ext_vector_type(8)));
typedef float f32x4 __attribute__((ext_vector_type(4)));

#define MTOT 8192
#define DM 1024
#define DI 256
#define TT 2048

__device__ __forceinline__ u16 f2bf(float f) {
    u32 u = __float_as_uint(f);
    return (u16)((u + 0x7fffu + ((u >> 16) & 1u)) >> 16);
}
__device__ __forceinline__ float b2f(u16 b) {
    return __uint_as_float((u32)b << 16);
}

// ================= prep: X cvt + wv cvt + 5 weight transposes in ONE launch =================
__device__ __forceinline__ void transpose_tile(const float* __restrict__ in,
                                               u16* __restrict__ out, int K, int N,
                                               int bx, int by) {
    __shared__ float t[32][33];
    int n0 = bx * 32, k0 = by * 32;
    int tx = threadIdx.x & 31, ty = threadIdx.x >> 5;
    #pragma unroll
    for (int i = ty; i < 32; i += 8) t[i][tx] = in[(long)(k0 + i) * N + n0 + tx];
    __syncthreads();
    #pragma unroll
    for (int i = ty; i < 32; i += 8) out[(long)(n0 + i) * K + k0 + tx] = f2bf(t[tx][i]);
}

__device__ __forceinline__ void cvt_range(const float* __restrict__ in,
                                          u16* __restrict__ out, long n4, int b, int nb) {
    long i = (long)b * 256 + threadIdx.x;
    long stride = (long)nb * 256;
    for (; i < n4; i += stride) {
        float4 v = reinterpret_cast<const float4*>(in)[i];
        union { u16 u[4]; uint2 p; } o;
        o.u[0] = f2bf(v.x); o.u[1] = f2bf(v.y); o.u[2] = f2bf(v.z); o.u[3] = f2bf(v.w);
        reinterpret_cast<uint2*>(out)[i] = o.p;
    }
}

__global__ __launch_bounds__(256) void prep_kernel(
    const float* __restrict__ x, u16* __restrict__ Xb,
    const float* __restrict__ wq, const float* __restrict__ wk, u16* __restrict__ Wqk_t,
    const float* __restrict__ wv, u16* __restrict__ Wv_b,
    const float* __restrict__ wo, u16* __restrict__ Wo_t,
    const float* __restrict__ w1, u16* __restrict__ W1_t,
    const float* __restrict__ w2, u16* __restrict__ W2_t)
{
    int b = blockIdx.x;
    if (b < 1024) { cvt_range(x, Xb, (long)MTOT * DM / 4, b, 1024); return; }
    b -= 1024;
    if (b < 256)  { transpose_tile(wq, Wqk_t,              1024,  256, b & 7,  b >> 3); return; }
    b -= 256;
    if (b < 256)  { transpose_tile(wk, Wqk_t + 256 * 1024, 1024,  256, b & 7,  b >> 3); return; }
    b -= 256;
    if (b < 256)  { cvt_range(wv, Wv_b, (long)DM * DM / 4, b, 256); return; }
    b -= 256;
    if (b < 1024) { transpose_tile(wo, Wo_t,               1024, 1024, b & 31, b >> 5); return; }
    b -= 1024;
    if (b < 256)  { transpose_tile(w1, W1_t,               1024,  256, b & 7,  b >> 3); return; }
    b -= 256;
    /* w2: (256,1024) -> (1024,256): 256 tiles */
    transpose_tile(w2, W2_t, 256, 1024, b & 31, b >> 5);
}

// ------- row softmax over T=2048: read raw bf16 scores, write fp32 attn + bf16 in place -------
__global__ __launch_bounds__(256) void softmax_kernel(u16* __restrict__ Sb, float* __restrict__ attn) {
    long row = blockIdx.x;
    int tid = threadIdx.x;
    uint4 q = reinterpret_cast<uint4*>(Sb + row * (long)TT)[tid];
    u32 w4[4] = {q.x, q.y, q.z, q.w};
    float vv[8];
    #pragma unroll
    for (int j = 0; j < 4; ++j) {
        vv[2 * j]     = __uint_as_float(w4[j] << 16);
        vv[2 * j + 1] = __uint_as_float(w4[j] & 0xffff0000u);
    }
    float m = vv[0];
    #pragma unroll
    for (int j = 1; j < 8; ++j) m = fmaxf(m, vv[j]);
    #pragma unroll
    for (int off = 32; off; off >>= 1) m = fmaxf(m, __shfl_xor(m, off));
    __shared__ float redm[4], reds[4];
    if ((tid & 63) == 0) redm[tid >> 6] = m;
    __syncthreads();
    m = fmaxf(fmaxf(redm[0], redm[1]), fmaxf(redm[2], redm[3]));
    float s = 0.f;
    #pragma unroll
    for (int j = 0; j < 8; ++j) { vv[j] = __expf(vv[j] - m); s += vv[j]; }
    #pragma unroll
    for (int off = 32; off; off >>= 1) s += __shfl_xor(s, off);
    if ((tid & 63) == 0) reds[tid >> 6] = s;
    __syncthreads();
    s = reds[0] + reds[1] + reds[2] + reds[3];
    float inv = 1.0f / s;
    #pragma unroll
    for (int j = 0; j < 8; ++j) vv[j] *= inv;
    float* p = attn + row * (long)TT;
    reinterpret_cast<float4*>(p)[tid * 2]     = make_float4(vv[0], vv[1], vv[2], vv[3]);
    reinterpret_cast<float4*>(p)[tid * 2 + 1] = make_float4(vv[4], vv[5], vv[6], vv[7]);
    union { u16 u[8]; uint4 q; } pk;
    #pragma unroll
    for (int j = 0; j < 8; ++j) pk.u[j] = f2bf(vv[j]);
    reinterpret_cast<uint4*>(Sb + row * (long)TT)[tid] = pk.q;
}

// ---------------- GEMM body: C = A (M,K) @ Bt^T, Bt stored (N,K). ----------------
// m97 structure: 128x128 tile, BK=64, 4 waves, global_load_lds(16B),
// XOR-swizzle (linear LDS dest + pre-swizzled global source + swizzled ds_read).
// MODE: 0 = bf16 C * scale    1 = bf16 C^T (transposed store)
//       3 = bf16 relu(C + bias)
//       6 = bf16 (C + bias + bf16_addend)      (PV+residual: bf16 out)
//       7 = fp32 (C + bias + bf16_addend)      (FFN2: final out)
template<int MODE>
__device__ __forceinline__ void gemm_body(
    u16* As, u16* Bs,
    const u16* __restrict__ A, int lda,
    const u16* __restrict__ Bt, int ldb,
    u16* __restrict__ Cb, int ldcb,
    float* __restrict__ Cf, int ldcf,
    int K, float scale,
    const float* __restrict__ bias,
    const u16* __restrict__ addend_b, int ld_add,
    long tile_m, long tile_n)
{
    const int tid = threadIdx.x;
    const int w = tid >> 6;
    const int l = tid & 63;
    const int lane15 = l & 15;
    const int lhi = l >> 4;

    // staging: each issue i covers 32 rows; lane l -> row w*8 + (l>>3) within the
    // 32-row chunk, 16B chunk (l&7) XOR-swizzled by row&7 (= l>>3).
    const int srow = w * 8 + (l >> 3);
    const int scol = (((l & 7) ^ (l >> 3)) << 4) >> 1; // element offset in row

    const u16* aptr = A + (tile_m + srow) * (long)lda + scol;
    const u16* bptr = Bt + (tile_n + srow) * (long)ldb + scol;

    f32x4 acc[4][4] = {};

    const int wr = (w >> 1) * 64;
    const int wc = (w & 1) * 64;

    for (int k0 = 0; k0 < K; k0 += 64) {
        #pragma unroll
        for (int i = 0; i < 4; ++i) {
            __builtin_amdgcn_global_load_lds(
                (const __attribute__((address_space(1))) void*)(aptr + (long)i * 32 * lda + k0),
                (__attribute__((address_space(3))) void*)((char*)As + i * 4096 + w * 1024),
                16, 0, 0);
        }
        #pragma unroll
        for (int i = 0; i < 4; ++i) {
            __builtin_amdgcn_global_load_lds(
                (const __attribute__((address_space(1))) void*)(bptr + (long)i * 32 * ldb + k0),
                (__attribute__((address_space(3))) void*)((char*)Bs + i * 4096 + w * 1024),
                16, 0, 0);
        }
        __syncthreads();
        #pragma unroll
        for (int kk = 0; kk < 2; ++kk) {
            bf16x8 af[4], bfr[4];
            const int kb = (kk * 32 + lhi * 8) * 2; // byte offset of k within row
            #pragma unroll
            for (int m = 0; m < 4; ++m) {
                int r = wr + m * 16 + lane15;
                af[m] = *reinterpret_cast<const bf16x8*>(
                    (const char*)As + r * 128 + (kb ^ ((r & 7) << 4)));
            }
            #pragma unroll
            for (int n = 0; n < 4; ++n) {
                int r = wc + n * 16 + lane15;
                bfr[n] = *reinterpret_cast<const bf16x8*>(
                    (const char*)Bs + r * 128 + (kb ^ ((r & 7) << 4)));
            }
            #pragma unroll
            for (int m = 0; m < 4; ++m)
                #pragma unroll
                for (int n = 0; n < 4; ++n)
                    acc[m][n] = __builtin_amdgcn_mfma_f32_16x16x32_bf16(
                        af[m], bfr[n], acc[m][n], 0, 0, 0);
        }
        __syncthreads();
    }

    // epilogue: C/D layout col = lane&15, row = (lane>>4)*4 + reg (m89-verified)
    #pragma unroll
    for (int m = 0; m < 4; ++m) {
        #pragma unroll
        for (int n = 0; n < 4; ++n) {
            long grow0 = tile_m + wr + m * 16 + lhi * 4;
            long gcol  = tile_n + wc + n * 16 + lane15;
            #pragma unroll
            for (int r = 0; r < 4; ++r) {
                long grow = grow0 + r;
                float v = acc[m][n][r];
                if (MODE == 0) v *= scale;
                if (MODE == 3 || MODE == 6 || MODE == 7) v += bias[gcol];
                if (MODE == 6 || MODE == 7) v += b2f(addend_b[grow * (long)ld_add + gcol]);
                if (MODE == 3) v = fmaxf(v, 0.0f);
                if (MODE == 0 || MODE == 3 || MODE == 6) Cb[grow * (long)ldcb + gcol] = f2bf(v);
                if (MODE == 1) Cb[gcol * (long)ldcb + grow] = f2bf(v);
                if (MODE == 7) Cf[grow * (long)ldcf + gcol] = v;
            }
        }
    }
}

// XCD-chunked bijective swizzle (valid because all grids are %8==0):
// hardware round-robins bid across 8 XCDs; logical id (bid&7)*cpx + bid>>3
// gives XCD j the contiguous logical chunk [j*cpx, (j+1)*cpx).
__device__ __forceinline__ int xcd_swizzle(int bid, int nb) {
    return (bid & 7) * (nb >> 3) + (bid >> 3);
}

template<int MODE>
__global__ __launch_bounds__(256) void gemm_bt(
    const u16* __restrict__ A, long sA, int lda,
    const u16* __restrict__ Bt, long sB, int ldb,
    u16* __restrict__ Cb, long sCb, int ldcb,
    float* __restrict__ Cf, long sCf, int ldcf,
    int K, float scale,
    const float* __restrict__ bias,
    const u16* __restrict__ addend_b, long sAdd, int ld_add,
    int gx, int gy)
{
    __shared__ __attribute__((aligned(16))) u16 As[128 * 64];
    __shared__ __attribute__((aligned(16))) u16 Bs[128 * 64];

    int lid = xcd_swizzle(blockIdx.x, gridDim.x);
    int x = lid % gx;
    int t = lid / gx;
    int y = t % gy;
    int z = t / gy;

    gemm_body<MODE>(As, Bs,
                    A + (long)z * sA, lda, Bt + (long)z * sB, ldb,
                    Cb + (long)z * sCb, ldcb, Cf + (long)z * sCf, ldcf,
                    K, scale, bias,
                    addend_b ? addend_b + (long)z * sAdd : addend_b, ld_add,
                    (long)y * 128, (long)x * 128);
}

// Merged QK + (X@Wvo)^T dispatch (both consume Xb as the A operand):
// logical ids [0,256):   QK = Xb @ Wqk_t^T (8192,512), gx=4, gy=64  (mode 0)
// logical ids [256,768): VW^T = (Xb @ Wvo_t^T)^T -> (1024,8192), gx=8, gy=64 (mode 1)
__global__ __launch_bounds__(256) void gemm_qkv(
    const u16* __restrict__ Xb, const u16* __restrict__ Wqk_t, u16* __restrict__ QKb,
    const u16* __restrict__ Wvo_t, u16* __restrict__ VWt)
{
    __shared__ __attribute__((aligned(16))) u16 As[128 * 64];
    __shared__ __attribute__((aligned(16))) u16 Bs[128 * 64];

    int lid = xcd_swizzle(blockIdx.x, gridDim.x);
    if (lid < 256) {
        int x = lid & 3, y = lid >> 2;
        gemm_body<0>(As, Bs, Xb, 1024, Wqk_t, 1024, QKb, 512,
                     (float*)nullptr, 0, 1024, 1.0f,
                     (const float*)nullptr, (const u16*)nullptr, 0,
                     (long)y * 128, (long)x * 128);
    } else {
        int l2 = lid - 256;
        int x = l2 & 7, y = l2 >> 3;
        gemm_body<1>(As, Bs, Xb, 1024, Wvo_t, 1024, VWt, 8192,
                     (float*)nullptr, 0, 1024, 1.0f,
                     (const float*)nullptr, (const u16*)nullptr, 0,
                     (long)y * 128, (long)x * 128);
    }
}

extern "C" void kernel_launch(void* const* d_in, const int* in_sizes, int n_in,
                              void* d_out, int out_size, void* d_ws, size_t ws_size,
                              hipStream_t stream)
{
    const float* x  = (const float*)d_in[0];
    const float* wq = (const float*)d_in[1];
    const float* wk = (const float*)d_in[2];
    const float* wv = (const float*)d_in[3];
    const float* wo = (const float*)d_in[4];
    const float* bo = (const float*)d_in[5];
    const float* w1 = (const float*)d_in[6];
    const float* b1 = (const float*)d_in[7];
    const float* w2 = (const float*)d_in[8];
    const float* b2 = (const float*)d_in[9];

    float* out_f  = (float*)d_out;
    float* attn_f = out_f + (long)MTOT * DM;  // second output, (4,2048,2048) fp32

    char* ws = (char*)d_ws;
    u16* Xb    = (u16*)(ws + 0);            // 16 MB bf16 X (also residual addend)
    u16* Wqk_t = (u16*)(ws + 16777216);     // 1 MB  (512,1024) = [wq^T ; wk^T]
    u16* Wv_b  = (u16*)(ws + 17825792);     // 2 MB  (1024,1024) wv straight bf16
    u16* Wo_t  = (u16*)(ws + 19922944);     // 2 MB  wo^T
    u16* W1_t  = (u16*)(ws + 22020096);     // 0.5 MB (256,1024)
    u16* W2_t  = (u16*)(ws + 22544384);     // 0.5 MB (1024,256)
    u16* Wvo_t = (u16*)(ws + 23068672);     // 2 MB  (Wv@Wo)^T (1024,1024)
    u16* QKb   = (u16*)(ws + 25165824);     // 8 MB  (8192,512) (reused as h)
    u16* VWt   = (u16*)(ws + 33554432);     // 16 MB (1024,8192)  (X@Wvo)^T
    u16* attnb = (u16*)(ws + 50331648);     // 32 MB (4,2048,2048) bf16: raw scores -> attn
    u16* res_b = (u16*)(ws + 83886080);     // 16 MB residual bf16
    u16* hb    = QKb;                       // alias: QK dead after scores GEMM

    dim3 blk(256);

    // 1. prep: X->bf16, wv->bf16, 5 weight transposes (one launch)
    prep_kernel<<<dim3(3328), blk, 0, stream>>>(x, Xb, wq, wk, Wqk_t, wv, Wv_b,
                                                wo, Wo_t, w1, W1_t, w2, W2_t);
    // 2. Wvo^T = (Wv @ Wo)^T  (1024,1024), mode 1
    gemm_bt<1><<<dim3(64), blk, 0, stream>>>(
        Wv_b, 0L, 1024, Wo_t, 0L, 1024, Wvo_t, 0L, 1024,
        (float*)nullptr, 0L, 0, 1024, 1.0f, (const float*)nullptr,
        (const u16*)nullptr, 0L, 0, 8, 8);
    // 3. merged QK (mode 0) + VW^T = (X @ Wvo)^T (mode 1)
    gemm_qkv<<<dim3(768), blk, 0, stream>>>(Xb, Wqk_t, QKb, Wvo_t, VWt);
    // 4. raw scores (bf16) = Q @ K^T * 1/16 -> attnb
    gemm_bt<0><<<dim3(1024), blk, 0, stream>>>(
        QKb, (long)2048 * 512, 512, QKb + 256, (long)2048 * 512, 512,
        attnb, (long)2048 * 2048, 2048, (float*)nullptr, 0L, 0,
        256, 0.0625f, (const float*)nullptr, (const u16*)nullptr, 0L, 0, 16, 16);
    // 5. softmax: attnb (raw bf16) -> attn_f fp32 (output) + attnb bf16 (in place)
    softmax_kernel<<<dim3(8192), blk, 0, stream>>>(attnb, attn_f);
    // 6. residual(bf16) = bf16(attn @ VW + bo + Xb)   (PV + Wo + residual fused)
    gemm_bt<6><<<dim3(512), blk, 0, stream>>>(
        attnb, (long)2048 * 2048, 2048, VWt, 2048L, 8192,
        res_b, (long)2048 * 1024, 1024, (float*)nullptr, 0L, 0,
        2048, 1.0f, bo, Xb, (long)2048 * 1024, 1024, 8, 16);
    // 7. h = relu(residual @ w1 + b1)  (8192,256)
    gemm_bt<3><<<dim3(128), blk, 0, stream>>>(
        res_b, 0L, 1024, W1_t, 0L, 1024, hb, 0L, 256,
        (float*)nullptr, 0L, 0, 1024, 1.0f, b1, (const u16*)nullptr, 0L, 0, 2, 64);
    // 8. out = residual + h @ w2 + b2  (fp32, first output)
    gemm_bt<7><<<dim3(512), blk, 0, stream>>>(
        hb, 0L, 256, W2_t, 0L, 256, (u16*)nullptr, 0L, 0,
        out_f, 0L, 1024, 256, 1.0f, b2, res_b, 0L, 1024, 8, 64);
}